// Round 8
// baseline (272.481 us; speedup 1.0000x reference)
//
#include <hip/hip_runtime.h>
#include <math.h>

// Problem constants
#define D    256      // feature dim (= C)
#define K    1024     // codebook size
#define HWX  1024     // H*W
#define NPTS 32768    // B*H*W
#define PT   64       // points per block (4 waves x 16 pts)
#define NPAIR 32      // 32-code pair-chunks per K-loop iteration

#define Q_OFF    1
#define PERP_OFF (1 + 8388608)
#define ENC_OFF  (2 + 8388608)

// ws layout: enorm f[1024] @0 ; counts i[1024] @4096 ; loss @8192 ; ticket @8200 ;
//            e-fragments (hi/lo bf16, MFMA B layout) @147456, 1 MB
#define WS_FRAG_OFF 147456

typedef __attribute__((ext_vector_type(8))) short bf16x8;
typedef __attribute__((ext_vector_type(4))) float f32x4;
typedef __attribute__((ext_vector_type(2))) float f32x2;

__device__ __forceinline__ unsigned short bf16_rne(float f) {
  unsigned int u = __float_as_uint(f);
  u = u + 0x7fffu + ((u >> 16) & 1u);
  return (unsigned short)(u >> 16);
}

#define CONV(F, H, L)                                                          \
  {                                                                            \
    H = bf16_rne(F);                                                           \
    const float fh_ = __uint_as_float((unsigned)(H) << 16);                    \
    L = bf16_rne((F)-fh_);                                                     \
  }

// Build e-fragments (hi/lo bf16, MFMA B layout); enorm; zero counts/loss/ticket.
// chunk cn (16 codes) = 16 KB contiguous at fragg + cn*16KB; within:
// frag(ks, part) = 1 KB at (ks*2+part)*1KB, lane-contiguous 16 B units.
__global__ __launch_bounds__(256) void vq_frag(const float* __restrict__ emb,
                                               unsigned int* __restrict__ frag,
                                               float* __restrict__ enorm,
                                               int* __restrict__ counts,
                                               float* __restrict__ loss_accum,
                                               unsigned int* __restrict__ ticket) {
  const int gid = blockIdx.x * 256 + threadIdx.x;  // 128 blocks -> 32768
  const int c = gid >> 5, g = gid & 31;            // code, k-group of 8
  const float* src = emb + (size_t)c * D + g * 8;
  const float4 a = *(const float4*)src;
  const float4 b = *(const float4*)(src + 4);
  float s = a.x * a.x + a.y * a.y + a.z * a.z + a.w * a.w +
            b.x * b.x + b.y * b.y + b.z * b.z + b.w * b.w;
#pragma unroll
  for (int off = 1; off < 32; off <<= 1) s += __shfl_xor(s, off);
  if (g == 0) enorm[c] = s;
  unsigned short h0, h1, h2, h3, h4, h5, h6, h7;
  unsigned short l0, l1, l2, l3, l4, l5, l6, l7;
  CONV(a.x, h0, l0) CONV(a.y, h1, l1) CONV(a.z, h2, l2) CONV(a.w, h3, l3)
  CONV(b.x, h4, l4) CONV(b.y, h5, l5) CONV(b.z, h6, l6) CONV(b.w, h7, l7)
  uint4 uh, ul;
  uh.x = (unsigned)h0 | ((unsigned)h1 << 16); uh.y = (unsigned)h2 | ((unsigned)h3 << 16);
  uh.z = (unsigned)h4 | ((unsigned)h5 << 16); uh.w = (unsigned)h6 | ((unsigned)h7 << 16);
  ul.x = (unsigned)l0 | ((unsigned)l1 << 16); ul.y = (unsigned)l2 | ((unsigned)l3 << 16);
  ul.z = (unsigned)l4 | ((unsigned)l5 << 16); ul.w = (unsigned)l6 | ((unsigned)l7 << 16);
  const int fragidx = (c >> 4) * 16 + (g >> 2) * 2;
  const int Lo = ((c & 15) + 16 * (g & 3)) * 4;
  *(uint4*)(frag + (size_t)fragidx * 256 + Lo) = uh;
  *(uint4*)(frag + (size_t)(fragidx + 1) * 256 + Lo) = ul;
  if (gid < K) counts[gid] = 0;
  if (gid == 0) { *loss_accum = 0.0f; *ticket = 0u; }
}

// async-stage one 32 KB chunk-pair (256 threads x 8 issues x 16 B)
#define ISSUE_PAIR(P, HALF)                                                    \
  {                                                                            \
    const unsigned* gsrc = fragg + (size_t)(P)*8192 + t * 4;                   \
    unsigned short* ldst = fbuf + (HALF)*16384 + t * 8;                        \
    _Pragma("unroll") for (int q = 0; q < 8; ++q)                              \
        __builtin_amdgcn_global_load_lds(                                      \
            (const __attribute__((address_space(1))) unsigned*)(gsrc + q * 1024), \
            (__attribute__((address_space(3))) unsigned*)(ldst + q * 2048),    \
            16, 0, 0);                                                         \
  }

// hoist A fragment for global k-slice KSv (single-pass layout: row w*8+KSv)
#define AHOIST(KSv)                                                            \
  ah##KSv = *(const bf16x8*)&fbuf[((w * 8 + (KSv)) * 2 + 0) * 512 + lane * 8]; \
  al##KSv = *(const bf16x8*)&fbuf[((w * 8 + (KSv)) * 2 + 1) * 512 + lane * 8];

// 3-pass hi/lo: x.e ~= xh.eh + xl.eh + xh.el  (xl.el ~ 2^-16, dropped)
// Generic over accumulator and buffer: the two chunks of a pair form two
// INDEPENDENT 24-MFMA chains (acc0/acc1), interleaved for MFMA-pipe ILP.
#define KS3G(KSv, ACC, BUFO)                                                   \
  {                                                                            \
    const bf16x8 bh = *(const bf16x8*)&fbuf[(BUFO) + ((KSv)*2 + 0) * 512 + lane * 8]; \
    const bf16x8 bl = *(const bf16x8*)&fbuf[(BUFO) + ((KSv)*2 + 1) * 512 + lane * 8]; \
    ACC = __builtin_amdgcn_mfma_f32_16x16x32_bf16(ah##KSv, bh, ACC, 0, 0, 0);  \
    ACC = __builtin_amdgcn_mfma_f32_16x16x32_bf16(al##KSv, bh, ACC, 0, 0, 0);  \
    ACC = __builtin_amdgcn_mfma_f32_16x16x32_bf16(ah##KSv, bl, ACC, 0, 0, 0);  \
  }

// score update for chunk-pair I (codes I*32 .. I*32+31) from half (I&1)
#define COMPUTE_PAIR(I)                                                        \
  {                                                                            \
    const int b0 = ((I)&1) * 16384;                                            \
    const int b1 = b0 + 8192;                                                  \
    f32x4 acc0 = {0.f, 0.f, 0.f, 0.f};                                         \
    f32x4 acc1 = {0.f, 0.f, 0.f, 0.f};                                         \
    __builtin_amdgcn_s_setprio(1);                                             \
    KS3G(0, acc0, b0) KS3G(0, acc1, b1)                                        \
    KS3G(1, acc0, b0) KS3G(1, acc1, b1)                                        \
    KS3G(2, acc0, b0) KS3G(2, acc1, b1)                                        \
    KS3G(3, acc0, b0) KS3G(3, acc1, b1)                                        \
    KS3G(4, acc0, b0) KS3G(4, acc1, b1)                                        \
    KS3G(5, acc0, b0) KS3G(5, acc1, b1)                                        \
    KS3G(6, acc0, b0) KS3G(6, acc1, b1)                                        \
    KS3G(7, acc0, b0) KS3G(7, acc1, b1)                                        \
    __builtin_amdgcn_s_setprio(0);                                             \
    const int c0 = (I)*32 + (lane & 15);                                       \
    const int c1 = c0 + 16;                                                    \
    const float e0 = en_s[c0], e1 = en_s[c1];                                  \
    float m;                                                                   \
    m = e0 - 2.0f * acc0[0]; if (m < mv[0]) { mv[0] = m; mi[0] = c0; }         \
    m = e0 - 2.0f * acc0[1]; if (m < mv[1]) { mv[1] = m; mi[1] = c0; }         \
    m = e0 - 2.0f * acc0[2]; if (m < mv[2]) { mv[2] = m; mi[2] = c0; }         \
    m = e0 - 2.0f * acc0[3]; if (m < mv[3]) { mv[3] = m; mi[3] = c0; }         \
    m = e1 - 2.0f * acc1[0]; if (m < mv[0]) { mv[0] = m; mi[0] = c1; }         \
    m = e1 - 2.0f * acc1[1]; if (m < mv[1]) { mv[1] = m; mi[1] = c1; }         \
    m = e1 - 2.0f * acc1[2]; if (m < mv[2]) { mv[2] = m; mi[2] = c1; }         \
    m = e1 - 2.0f * acc1[3]; if (m < mv[3]) { mv[3] = m; mi[3] = c1; }         \
  }

// 32 B of one-hot zeros per thread per iter; 32 iters cover the 256 KB slice.
#define ENC_ZERO2(I)                                                           \
  {                                                                            \
    const f32x2 z_ = {0.f, 0.f};                                               \
    __builtin_nontemporal_store(z_, encz + (I)*1024 + t);                      \
    __builtin_nontemporal_store(z_, encz + (I)*1024 + 256 + t);                \
    __builtin_nontemporal_store(z_, encz + (I)*1024 + 512 + t);                \
    __builtin_nontemporal_store(z_, encz + (I)*1024 + 768 + t);                \
  }

// compiler-only ordering fence (no instruction): pins VMEM issue order so the
// counted vmcnt arithmetic below stays valid under scheduling.
#define CFENCE asm volatile("" ::: "memory");

__global__ __launch_bounds__(256) void vq_main(const float* __restrict__ x,
                                               const unsigned int* __restrict__ fragg,
                                               const float* __restrict__ emb,
                                               const float* __restrict__ enorm,
                                               float* __restrict__ out,
                                               float* __restrict__ loss_accum,
                                               int* __restrict__ counts,
                                               unsigned int* __restrict__ ticket) {
  // fbuf phases: x transit (64 KB, single pass) -> e pair dbuf (2x32 KB) -> xq
  __shared__ __align__(16) unsigned short fbuf[32768];  // 64 KB
  __shared__ float en_s[K];                             // 4 KB
  __shared__ float xn_part[256];
  __shared__ float val_s[PT];
  __shared__ int idx_s[PT];
  __shared__ unsigned int rank_s;
  // LDS total: ~71.2 KB -> 2 blocks/CU (142 of 160 KB; clear of R5 cliff).

  float* out_q = out + Q_OFF;
  float* out_enc = out + ENC_OFF;

  const int t = threadIdx.x;
  const int lane = t & 63;
  const int w = t >> 6;        // wave id; wave owns points w*16..w*16+15
  const int p0 = blockIdx.x * PT;
  const int bb = p0 >> 10;
  const int hw0 = p0 & 1023;

  bf16x8 ah0, ah1, ah2, ah3, ah4, ah5, ah6, ah7;
  bf16x8 al0, al1, al2, al3, al4, al5, al6, al7;
  float xn_acc = 0.0f;

  // ---- prologue: stage x (single 64 KB pass), hoist A to registers ----
  // 4 threads per point, 64 channels each; row (pt>>4)*8 + ks, hi/lo at +512.
  {
    const int pt = t & 63, cb_ = t >> 6;
    const float* xb = x + (size_t)bb * (D * HWX) + hw0 + pt;
#pragma unroll 8
    for (int i = 0; i < 64; ++i) {
      const int c = cb_ + 4 * i;
      const float f = xb[(size_t)c * HWX];
      unsigned short h_, l_;
      CONV(f, h_, l_)
      xn_acc += f * f;
      const int ks = c >> 5, quad = (c >> 3) & 3, j = c & 7;
      const int base =
          (((pt >> 4) * 8 + ks) * 2) * 512 + ((pt & 15) + 16 * quad) * 8 + j;
      fbuf[base] = h_;
      fbuf[base + 512] = l_;
    }
  }
  for (int i = t; i < K; i += 256) en_s[i] = enorm[i];
  xn_part[t] = xn_acc;
  __syncthreads();
  AHOIST(0) AHOIST(1) AHOIST(2) AHOIST(3)
  AHOIST(4) AHOIST(5) AHOIST(6) AHOIST(7)
  __syncthreads();  // hoists done (lgkm drained by syncthreads); fbuf free

  float mv[4];
  int mi[4];
#pragma unroll
  for (int i = 0; i < 4; ++i) { mv[i] = 3.4e38f; mi[i] = 0; }

  f32x2* encz = reinterpret_cast<f32x2*>(out_enc + (size_t)p0 * K);

  // ---- K-loop: 32 pair-iterations, 2x32 KB double buffer, counted vmcnt.
  // Per-iter VMEM issue order (pinned by CFENCE): [8L(pair i+1)][4S(enc i)].
  // Wait at END of iter i: vmcnt(4) -> in-order retirement drains everything
  // older than the newest 4 stores, i.e. all 8 loads of pair i+1 (+ stores
  // from iter i-1, which had a full iteration to retire). Loads get the whole
  // COMPUTE_PAIR(i) (~2-4K cyc) to land from L2.  Barrier then republishes
  // the freshly-loaded half; the half being overwritten next iter was last
  // read at iter i-1, protected by that iteration's end barrier.
  ISSUE_PAIR(0, 0)
  asm volatile("s_waitcnt vmcnt(0)" ::: "memory");
  __builtin_amdgcn_s_barrier();
  for (int i = 0; i < NPAIR - 1; ++i) {
    CFENCE
    ISSUE_PAIR(i + 1, (i + 1) & 1)
    CFENCE
    ENC_ZERO2(i)
    CFENCE
    COMPUTE_PAIR(i)
    asm volatile("s_waitcnt vmcnt(4)" ::: "memory");
    __builtin_amdgcn_s_barrier();
  }
  CFENCE
  ENC_ZERO2(NPAIR - 1)
  COMPUTE_PAIR(NPAIR - 1)  // half (31&1)=1, loaded at iter 30

  // ---- wave-local argmin butterfly over 16 lane-columns (first-index ties) ----
#pragma unroll
  for (int off = 1; off < 16; off <<= 1) {
#pragma unroll
    for (int i = 0; i < 4; ++i) {
      const float ov = __shfl_xor(mv[i], off);
      const int oi = __shfl_xor(mi[i], off);
      if (ov < mv[i] || (ov == mv[i] && oi < mi[i])) { mv[i] = ov; mi[i] = oi; }
    }
  }
  if ((lane & 15) == 0) {
    const int quad = lane >> 4;  // D-layout: row = quad*4 + reg
#pragma unroll
    for (int i = 0; i < 4; ++i) {
      val_s[w * 16 + quad * 4 + i] = mv[i];
      idx_s[w * 16 + quad * 4 + i] = mi[i];
    }
  }
  // drain all enc-zero stores (every thread) before the ones-scatter; also
  // syncs val_s/idx_s and frees fbuf for the xq phase.
  asm volatile("s_waitcnt vmcnt(0)" ::: "memory");
  __syncthreads();

  float dist = 0.0f;
  if (t < PT) {
    float xn = 0.0f;
#pragma unroll
    for (int g = 0; g < 4; ++g) xn += xn_part[t + 64 * g];
    dist = val_s[t] + xn;  // = ||x||^2 + ||e||^2 - 2 x.e
    atomicAdd(&counts[idx_s[t]], 1);
    out_enc[(size_t)(p0 + t) * K + idx_s[t]] = 1.0f;  // the one-hot ones
  }
  if (t < 64) {
#pragma unroll
    for (int off = 32; off > 0; off >>= 1) dist += __shfl_down(dist, off);
    if (t == 0) atomicAdd(loss_accum, dist);
  }

  // ---- quantized NCHW via staged gather (four 16-row quarters in fbuf) ----
  float* xq = (float*)fbuf;  // 16*257 floats = 16.4 KB
  for (int qd = 0; qd < 4; ++qd) {
    __syncthreads();  // xq free (qd=0: also past K-loop readers)
#pragma unroll
    for (int rr = 0; rr < 4; ++rr) {  // 4 rows per wave, coalesced 1 KB row loads
      const int r = w * 4 + rr;
      const float4 v = ((const float4*)(emb + (size_t)idx_s[qd * 16 + r] * D))[lane];
      float* dst = &xq[r * 257 + lane];
      dst[0] = v.x; dst[64] = v.y; dst[128] = v.z; dst[192] = v.w;
    }
    __syncthreads();
    const int pt = t & 15;
    float* qb = out_q + (size_t)bb * D * HWX + hw0 + qd * 16 + pt;
#pragma unroll
    for (int ii = 0; ii < 16; ++ii) {
      const int ci = (t >> 4) + 16 * ii;
      const int pos = (ci >> 2) + 64 * (ci & 3);  // inverse of store permutation
      qb[(size_t)ci * HWX] = xq[pt * 257 + pos];
    }
  }

  // ---- last-block ticket: fold the final reduction into this kernel ----
  // counts/loss contributions are atomics, drained (vmcnt) before the barrier;
  // release fence before ticket, acquire fence after winning.
  asm volatile("s_waitcnt vmcnt(0)" ::: "memory");
  __syncthreads();
  if (t == 0) {
    __threadfence();
    rank_s = atomicAdd(ticket, 1u);
  }
  __syncthreads();
  if (rank_s == (unsigned)(NPTS / PT) - 1u) {
    __threadfence();
    float s = 0.0f;
    for (int k = t; k < K; k += 256) {
      const int c = __hip_atomic_load(&counts[k], __ATOMIC_RELAXED,
                                      __HIP_MEMORY_SCOPE_AGENT);
      const float p = (float)c * (1.0f / 32768.0f);
      s += p * logf(p + 1e-10f);
    }
#pragma unroll
    for (int off = 32; off > 0; off >>= 1) s += __shfl_down(s, off);
    if (lane == 0) val_s[w] = s;
    __syncthreads();
    if (t == 0) {
      const float tot = val_s[0] + val_s[1] + val_s[2] + val_s[3];
      const float loss = __hip_atomic_load(loss_accum, __ATOMIC_RELAXED,
                                           __HIP_MEMORY_SCOPE_AGENT);
      out[PERP_OFF] = expf(-tot);
      out[0] = 0.25f * loss / 8388608.0f;
    }
  }
}

extern "C" void kernel_launch(void* const* d_in, const int* in_sizes, int n_in,
                              void* d_out, int out_size, void* d_ws, size_t ws_size,
                              hipStream_t stream) {
  const float* x = (const float*)d_in[0];     // [32,256,32,32] fp32 NCHW
  const float* emb = (const float*)d_in[1];   // [1024,256] fp32
  float* out = (float*)d_out;
  float* enorm = (float*)d_ws;
  int* counts = (int*)((char*)d_ws + 4096);
  float* loss_accum = (float*)((char*)d_ws + 8192);
  unsigned int* ticket = (unsigned int*)((char*)d_ws + 8200);
  unsigned int* fragg = (unsigned int*)((char*)d_ws + WS_FRAG_OFF);  // 1 MB

  hipLaunchKernelGGL(vq_frag, dim3(128), dim3(256), 0, stream,
                     emb, fragg, enorm, counts, loss_accum, ticket);
  hipLaunchKernelGGL(vq_main, dim3(NPTS / PT), dim3(256), 0, stream,
                     x, fragg, emb, enorm, out, loss_accum, counts, ticket);
}

// Round 9
// 244.622 us; speedup vs baseline: 1.1139x; 1.1139x over previous
//
#include <hip/hip_runtime.h>
#include <math.h>

// Problem constants
#define D    256      // feature dim (= C)
#define K    1024     // codebook size
#define HWX  1024     // H*W
#define NPTS 32768    // B*H*W
#define PT   64       // points per block (4 waves x 16 pts)
#define NPAIR 32      // 32-code pair-chunks per K-loop iteration

#define Q_OFF    1
#define PERP_OFF (1 + 8388608)
#define ENC_OFF  (2 + 8388608)

// ws layout: enorm f[1024] @0 ; counts i[1024] @4096 ; loss @8192 ; ticket @8200 ;
//            e-fragments (hi/lo bf16, MFMA B layout) @147456, 1 MB
#define WS_FRAG_OFF 147456

typedef __attribute__((ext_vector_type(8))) short bf16x8;
typedef __attribute__((ext_vector_type(4))) float f32x4;
typedef __attribute__((ext_vector_type(2))) float f32x2;

__device__ __forceinline__ unsigned short bf16_rne(float f) {
  unsigned int u = __float_as_uint(f);
  u = u + 0x7fffu + ((u >> 16) & 1u);
  return (unsigned short)(u >> 16);
}

#define CONV(F, H, L)                                                          \
  {                                                                            \
    H = bf16_rne(F);                                                           \
    const float fh_ = __uint_as_float((unsigned)(H) << 16);                    \
    L = bf16_rne((F)-fh_);                                                     \
  }

// Build e-fragments (hi/lo bf16, MFMA B layout); enorm; zero counts/loss/ticket.
// chunk cn (16 codes) = 16 KB contiguous at fragg + cn*16KB; within:
// frag(ks, part) = 1 KB at (ks*2+part)*1KB, lane-contiguous 16 B units.
__global__ __launch_bounds__(256) void vq_frag(const float* __restrict__ emb,
                                               unsigned int* __restrict__ frag,
                                               float* __restrict__ enorm,
                                               int* __restrict__ counts,
                                               float* __restrict__ loss_accum,
                                               unsigned int* __restrict__ ticket) {
  const int gid = blockIdx.x * 256 + threadIdx.x;  // 128 blocks -> 32768
  const int c = gid >> 5, g = gid & 31;            // code, k-group of 8
  const float* src = emb + (size_t)c * D + g * 8;
  const float4 a = *(const float4*)src;
  const float4 b = *(const float4*)(src + 4);
  float s = a.x * a.x + a.y * a.y + a.z * a.z + a.w * a.w +
            b.x * b.x + b.y * b.y + b.z * b.z + b.w * b.w;
#pragma unroll
  for (int off = 1; off < 32; off <<= 1) s += __shfl_xor(s, off);
  if (g == 0) enorm[c] = s;
  unsigned short h0, h1, h2, h3, h4, h5, h6, h7;
  unsigned short l0, l1, l2, l3, l4, l5, l6, l7;
  CONV(a.x, h0, l0) CONV(a.y, h1, l1) CONV(a.z, h2, l2) CONV(a.w, h3, l3)
  CONV(b.x, h4, l4) CONV(b.y, h5, l5) CONV(b.z, h6, l6) CONV(b.w, h7, l7)
  uint4 uh, ul;
  uh.x = (unsigned)h0 | ((unsigned)h1 << 16); uh.y = (unsigned)h2 | ((unsigned)h3 << 16);
  uh.z = (unsigned)h4 | ((unsigned)h5 << 16); uh.w = (unsigned)h6 | ((unsigned)h7 << 16);
  ul.x = (unsigned)l0 | ((unsigned)l1 << 16); ul.y = (unsigned)l2 | ((unsigned)l3 << 16);
  ul.z = (unsigned)l4 | ((unsigned)l5 << 16); ul.w = (unsigned)l6 | ((unsigned)l7 << 16);
  const int fragidx = (c >> 4) * 16 + (g >> 2) * 2;
  const int Lo = ((c & 15) + 16 * (g & 3)) * 4;
  *(uint4*)(frag + (size_t)fragidx * 256 + Lo) = uh;
  *(uint4*)(frag + (size_t)(fragidx + 1) * 256 + Lo) = ul;
  if (gid < K) counts[gid] = 0;
  if (gid == 0) { *loss_accum = 0.0f; *ticket = 0u; }
}

// async-stage one 32 KB chunk-pair (256 threads x 8 issues x 16 B)
#define ISSUE_PAIR(P, HALF)                                                    \
  {                                                                            \
    const unsigned* gsrc = fragg + (size_t)(P)*8192 + t * 4;                   \
    unsigned short* ldst = fbuf + (HALF)*16384 + t * 8;                        \
    _Pragma("unroll") for (int q = 0; q < 8; ++q)                              \
        __builtin_amdgcn_global_load_lds(                                      \
            (const __attribute__((address_space(1))) unsigned*)(gsrc + q * 1024), \
            (__attribute__((address_space(3))) unsigned*)(ldst + q * 2048),    \
            16, 0, 0);                                                         \
  }

// hoist A fragment for global k-slice KSv (single-pass layout: row w*8+KSv)
#define AHOIST(KSv)                                                            \
  ah##KSv = *(const bf16x8*)&fbuf[((w * 8 + (KSv)) * 2 + 0) * 512 + lane * 8]; \
  al##KSv = *(const bf16x8*)&fbuf[((w * 8 + (KSv)) * 2 + 1) * 512 + lane * 8];

// 3-pass hi/lo: x.e ~= xh.eh + xl.eh + xh.el  (xl.el ~ 2^-16, dropped)
// Generic over accumulator and buffer: the two chunks of a pair form two
// INDEPENDENT 24-MFMA chains (acc0/acc1), interleaved for MFMA-pipe ILP.
#define KS3G(KSv, ACC, BUFO)                                                   \
  {                                                                            \
    const bf16x8 bh = *(const bf16x8*)&fbuf[(BUFO) + ((KSv)*2 + 0) * 512 + lane * 8]; \
    const bf16x8 bl = *(const bf16x8*)&fbuf[(BUFO) + ((KSv)*2 + 1) * 512 + lane * 8]; \
    ACC = __builtin_amdgcn_mfma_f32_16x16x32_bf16(ah##KSv, bh, ACC, 0, 0, 0);  \
    ACC = __builtin_amdgcn_mfma_f32_16x16x32_bf16(al##KSv, bh, ACC, 0, 0, 0);  \
    ACC = __builtin_amdgcn_mfma_f32_16x16x32_bf16(ah##KSv, bl, ACC, 0, 0, 0);  \
  }

// score update for chunk-pair I (codes I*32 .. I*32+31) from half (I&1)
#define COMPUTE_PAIR(I)                                                        \
  {                                                                            \
    const int b0 = ((I)&1) * 16384;                                            \
    const int b1 = b0 + 8192;                                                  \
    f32x4 acc0 = {0.f, 0.f, 0.f, 0.f};                                         \
    f32x4 acc1 = {0.f, 0.f, 0.f, 0.f};                                         \
    KS3G(0, acc0, b0) KS3G(0, acc1, b1)                                        \
    KS3G(1, acc0, b0) KS3G(1, acc1, b1)                                        \
    KS3G(2, acc0, b0) KS3G(2, acc1, b1)                                        \
    KS3G(3, acc0, b0) KS3G(3, acc1, b1)                                        \
    KS3G(4, acc0, b0) KS3G(4, acc1, b1)                                        \
    KS3G(5, acc0, b0) KS3G(5, acc1, b1)                                        \
    KS3G(6, acc0, b0) KS3G(6, acc1, b1)                                        \
    KS3G(7, acc0, b0) KS3G(7, acc1, b1)                                        \
    const int c0 = (I)*32 + (lane & 15);                                       \
    const int c1 = c0 + 16;                                                    \
    const float e0 = en_s[c0], e1 = en_s[c1];                                  \
    float m;                                                                   \
    m = e0 - 2.0f * acc0[0]; if (m < mv[0]) { mv[0] = m; mi[0] = c0; }         \
    m = e0 - 2.0f * acc0[1]; if (m < mv[1]) { mv[1] = m; mi[1] = c0; }         \
    m = e0 - 2.0f * acc0[2]; if (m < mv[2]) { mv[2] = m; mi[2] = c0; }         \
    m = e0 - 2.0f * acc0[3]; if (m < mv[3]) { mv[3] = m; mi[3] = c0; }         \
    m = e1 - 2.0f * acc1[0]; if (m < mv[0]) { mv[0] = m; mi[0] = c1; }         \
    m = e1 - 2.0f * acc1[1]; if (m < mv[1]) { mv[1] = m; mi[1] = c1; }         \
    m = e1 - 2.0f * acc1[2]; if (m < mv[2]) { mv[2] = m; mi[2] = c1; }         \
    m = e1 - 2.0f * acc1[3]; if (m < mv[3]) { mv[3] = m; mi[3] = c1; }         \
  }

// 32 B of one-hot zeros per thread per iter; 32 iters cover the 256 KB slice.
#define ENC_ZERO2(I)                                                           \
  {                                                                            \
    const f32x2 z_ = {0.f, 0.f};                                               \
    __builtin_nontemporal_store(z_, encz + (I)*1024 + t);                      \
    __builtin_nontemporal_store(z_, encz + (I)*1024 + 256 + t);                \
    __builtin_nontemporal_store(z_, encz + (I)*1024 + 512 + t);                \
    __builtin_nontemporal_store(z_, encz + (I)*1024 + 768 + t);                \
  }

// compiler-only ordering fence (no instruction): pins VMEM issue order so the
// counted vmcnt arithmetic below stays valid under scheduling.
#define CFENCE asm volatile("" ::: "memory");

__global__ __launch_bounds__(256) void vq_main(const float* __restrict__ x,
                                               const unsigned int* __restrict__ fragg,
                                               const float* __restrict__ emb,
                                               const float* __restrict__ enorm,
                                               float* __restrict__ out,
                                               float* __restrict__ loss_accum,
                                               int* __restrict__ counts,
                                               unsigned int* __restrict__ ticket) {
  // fbuf phases: x transit (64 KB, single pass) -> e pair dbuf (2x32 KB) -> xq
  __shared__ __align__(16) unsigned short fbuf[32768];  // 64 KB
  __shared__ float en_s[K];                             // 4 KB
  __shared__ float xn_part[256];
  __shared__ float val_s[PT];
  __shared__ int idx_s[PT];
  __shared__ unsigned int rank_s;
  // LDS total: ~71.2 KB -> 2 blocks/CU (142 of 160 KB; clear of R5 cliff).

  float* out_q = out + Q_OFF;
  float* out_enc = out + ENC_OFF;

  const int t = threadIdx.x;
  const int lane = t & 63;
  const int w = t >> 6;        // wave id; wave owns points w*16..w*16+15
  const int p0 = blockIdx.x * PT;
  const int bb = p0 >> 10;
  const int hw0 = p0 & 1023;

  bf16x8 ah0, ah1, ah2, ah3, ah4, ah5, ah6, ah7;
  bf16x8 al0, al1, al2, al3, al4, al5, al6, al7;
  float xn_acc = 0.0f;

  // ---- prologue: stage x (single 64 KB pass), hoist A to registers ----
  // 4 threads per point, 64 channels each; row (pt>>4)*8 + ks, hi/lo at +512.
  {
    const int pt = t & 63, cb_ = t >> 6;
    const float* xb = x + (size_t)bb * (D * HWX) + hw0 + pt;
#pragma unroll 8
    for (int i = 0; i < 64; ++i) {
      const int c = cb_ + 4 * i;
      const float f = xb[(size_t)c * HWX];
      unsigned short h_, l_;
      CONV(f, h_, l_)
      xn_acc += f * f;
      const int ks = c >> 5, quad = (c >> 3) & 3, j = c & 7;
      const int base =
          (((pt >> 4) * 8 + ks) * 2) * 512 + ((pt & 15) + 16 * quad) * 8 + j;
      fbuf[base] = h_;
      fbuf[base + 512] = l_;
    }
  }
  for (int i = t; i < K; i += 256) en_s[i] = enorm[i];
  xn_part[t] = xn_acc;
  __syncthreads();
  AHOIST(0) AHOIST(1) AHOIST(2) AHOIST(3)
  AHOIST(4) AHOIST(5) AHOIST(6) AHOIST(7)
  __syncthreads();  // hoists done (lgkm drained by syncthreads); fbuf free

  float mv[4];
  int mi[4];
#pragma unroll
  for (int i = 0; i < 4; ++i) { mv[i] = 3.4e38f; mi[i] = 0; }

  f32x2* encz = reinterpret_cast<f32x2*>(out_enc + (size_t)p0 * K);

  // ---- K-loop: 32 pair-iterations, 2x32 KB double buffer, counted vmcnt.
  // Per-iter VMEM issue order (pinned by CFENCE): [8L(pair i+1)][4S(enc i)].
  // Wait at END of iter i: vmcnt(4) -> in-order retirement drains everything
  // older than the newest 4 stores, i.e. all 8 loads of pair i+1 (+ stores
  // from iter i-1, which had a full iteration to retire). Loads get the whole
  // COMPUTE_PAIR(i) (~2-4K cyc) to land from L2.  Barrier then republishes
  // the freshly-loaded half; the half being overwritten next iter was last
  // read at iter i-1, protected by that iteration's end barrier.
  ISSUE_PAIR(0, 0)
  asm volatile("s_waitcnt vmcnt(0)" ::: "memory");
  __builtin_amdgcn_s_barrier();
  for (int i = 0; i < NPAIR - 1; ++i) {
    CFENCE
    ISSUE_PAIR(i + 1, (i + 1) & 1)
    CFENCE
    ENC_ZERO2(i)
    CFENCE
    COMPUTE_PAIR(i)
    asm volatile("s_waitcnt vmcnt(4)" ::: "memory");
    __builtin_amdgcn_s_barrier();
  }
  CFENCE
  ENC_ZERO2(NPAIR - 1)
  COMPUTE_PAIR(NPAIR - 1)  // half (31&1)=1, loaded at iter 30

  // ---- wave-local argmin butterfly over 16 lane-columns (first-index ties) ----
#pragma unroll
  for (int off = 1; off < 16; off <<= 1) {
#pragma unroll
    for (int i = 0; i < 4; ++i) {
      const float ov = __shfl_xor(mv[i], off);
      const int oi = __shfl_xor(mi[i], off);
      if (ov < mv[i] || (ov == mv[i] && oi < mi[i])) { mv[i] = ov; mi[i] = oi; }
    }
  }
  if ((lane & 15) == 0) {
    const int quad = lane >> 4;  // D-layout: row = quad*4 + reg
#pragma unroll
    for (int i = 0; i < 4; ++i) {
      val_s[w * 16 + quad * 4 + i] = mv[i];
      idx_s[w * 16 + quad * 4 + i] = mi[i];
    }
  }
  // drain all enc-zero stores (every thread) before the ones-scatter; also
  // syncs val_s/idx_s and frees fbuf for the xq phase.
  asm volatile("s_waitcnt vmcnt(0)" ::: "memory");
  __syncthreads();

  float dist = 0.0f;
  if (t < PT) {
    float xn = 0.0f;
#pragma unroll
    for (int g = 0; g < 4; ++g) xn += xn_part[t + 64 * g];
    dist = val_s[t] + xn;  // = ||x||^2 + ||e||^2 - 2 x.e
    atomicAdd(&counts[idx_s[t]], 1);
    out_enc[(size_t)(p0 + t) * K + idx_s[t]] = 1.0f;  // the one-hot ones
  }
  if (t < 64) {
#pragma unroll
    for (int off = 32; off > 0; off >>= 1) dist += __shfl_down(dist, off);
    if (t == 0) atomicAdd(loss_accum, dist);
  }

  // ---- quantized NCHW via staged gather (four 16-row quarters in fbuf) ----
  float* xq = (float*)fbuf;  // 16*257 floats = 16.4 KB
  for (int qd = 0; qd < 4; ++qd) {
    __syncthreads();  // xq free (qd=0: also past K-loop readers)
#pragma unroll
    for (int rr = 0; rr < 4; ++rr) {  // 4 rows per wave, coalesced 1 KB row loads
      const int r = w * 4 + rr;
      const float4 v = ((const float4*)(emb + (size_t)idx_s[qd * 16 + r] * D))[lane];
      float* dst = &xq[r * 257 + lane];
      dst[0] = v.x; dst[64] = v.y; dst[128] = v.z; dst[192] = v.w;
    }
    __syncthreads();
    const int pt = t & 15;
    float* qb = out_q + (size_t)bb * D * HWX + hw0 + qd * 16 + pt;
#pragma unroll
    for (int ii = 0; ii < 16; ++ii) {
      const int ci = (t >> 4) + 16 * ii;
      const int pos = (ci >> 2) + 64 * (ci & 3);  // inverse of store permutation
      qb[(size_t)ci * HWX] = xq[pt * 257 + pos];
    }
  }

  // ---- last-block ticket: fold the final reduction into this kernel ----
  // No __threadfence (R8's buffer_wbl2 flush x512 blocks was the regressor):
  // the vmcnt(0) drain below retires this block's device-scope counts/loss
  // atomics to the coherent point BEFORE the ticket atomic issues; the winner
  // reads them with agent-scope atomic loads that bypass stale caches.
  asm volatile("s_waitcnt vmcnt(0)" ::: "memory");
  __syncthreads();
  if (t == 0) rank_s = atomicAdd(ticket, 1u);
  __syncthreads();
  if (rank_s == (unsigned)(NPTS / PT) - 1u) {
    float s = 0.0f;
    for (int k = t; k < K; k += 256) {
      const int c = __hip_atomic_load(&counts[k], __ATOMIC_RELAXED,
                                      __HIP_MEMORY_SCOPE_AGENT);
      const float p = (float)c * (1.0f / 32768.0f);
      s += p * logf(p + 1e-10f);
    }
#pragma unroll
    for (int off = 32; off > 0; off >>= 1) s += __shfl_down(s, off);
    if (lane == 0) val_s[w] = s;
    __syncthreads();
    if (t == 0) {
      const float tot = val_s[0] + val_s[1] + val_s[2] + val_s[3];
      const float loss = __hip_atomic_load(loss_accum, __ATOMIC_RELAXED,
                                           __HIP_MEMORY_SCOPE_AGENT);
      out[PERP_OFF] = expf(-tot);
      out[0] = 0.25f * loss / 8388608.0f;
    }
  }
}

extern "C" void kernel_launch(void* const* d_in, const int* in_sizes, int n_in,
                              void* d_out, int out_size, void* d_ws, size_t ws_size,
                              hipStream_t stream) {
  const float* x = (const float*)d_in[0];     // [32,256,32,32] fp32 NCHW
  const float* emb = (const float*)d_in[1];   // [1024,256] fp32
  float* out = (float*)d_out;
  float* enorm = (float*)d_ws;
  int* counts = (int*)((char*)d_ws + 4096);
  float* loss_accum = (float*)((char*)d_ws + 8192);
  unsigned int* ticket = (unsigned int*)((char*)d_ws + 8200);
  unsigned int* fragg = (unsigned int*)((char*)d_ws + WS_FRAG_OFF);  // 1 MB

  hipLaunchKernelGGL(vq_frag, dim3(128), dim3(256), 0, stream,
                     emb, fragg, enorm, counts, loss_accum, ticket);
  hipLaunchKernelGGL(vq_main, dim3(NPTS / PT), dim3(256), 0, stream,
                     x, fragg, emb, enorm, out, loss_accum, counts, ticket);
}